// Round 2
// baseline (633.279 us; speedup 1.0000x reference)
//
#include <hip/hip_runtime.h>

#define IN_DIM 1024
#define HID_DIM 2048
#define T_DIM 256

typedef __attribute__((ext_vector_type(4))) float floatx4;
typedef __attribute__((ext_vector_type(8))) short shortx8;   // 8 bf16 (4 VGPRs)

__device__ __forceinline__ unsigned bf_rnd(float f) {
  // fp32 -> bf16 RNE, result in high 16 bits
  unsigned u = __builtin_bit_cast(unsigned, f);
  return u + 0x7fffu + ((u >> 16) & 1u);
}

// returns (bf16(fhi) << 16) | bf16(flo)  -- one v_perm_b32 for the pack
__device__ __forceinline__ unsigned pack_bf16(float flo, float fhi) {
  return __builtin_amdgcn_perm(bf_rnd(fhi), bf_rnd(flo), 0x07060302u);
}

__global__ __launch_bounds__(256) void cat_linear_kernel(
    const float* __restrict__ x, const int* __restrict__ cat_ids,
    const float* __restrict__ W, const float* __restrict__ bias,
    float* __restrict__ out) {
  const int nt = blockIdx.x;   // 0..15  (hidden tiles)
  const int mt = blockIdx.y;   // 0..1   (token tiles)
  const int b  = blockIdx.z;   // 0..63  (batch)
  const int tid = threadIdx.x;
  const int c = cat_ids[b];

  const int n0 = nt * 128;
  const float* xb = x + ((size_t)b * T_DIM + (size_t)mt * 128) * IN_DIM;
  const float* Wc = W + (size_t)c * IN_DIM * HID_DIM + n0;

  // A: [m][k] row-major, BK=32, 64B rows (m97-proven read pattern)
  __shared__ __attribute__((aligned(16))) unsigned short As[128 * 32];   // 8 KB
  // B: [n][k] transposed tile, 40 shorts/row (80B): b128 reads land on 8
  // distinct 4-bank groups tiling all 32 banks (2-way = free, m136)
  __shared__ __attribute__((aligned(16))) unsigned short Bs[128 * 40];   // 10 KB

  const int lane = tid & 63;
  const int wv   = tid >> 6;         // wave 0..3 -> 2x2
  const int wm   = (wv >> 1) * 64;
  const int wn   = (wv & 1) * 64;
  const int l16  = lane & 15;
  const int quad = lane >> 4;

  floatx4 acc[4][4] = {};

  // A staging: thread covers row ar(+p*32), 4 k-cols
  const int ar = tid >> 3;
  const int ac = (tid & 7) * 4;
  // B staging: thread covers k-group g (8 rows), n-pair (2u, 2u+1)
  const int g  = tid & 3;
  const int u  = tid >> 2;           // 0..63
  const float* wptr = Wc + (size_t)(8 * g) * HID_DIM + 2 * u;
  const float* aptr = xb + (size_t)ar * IN_DIM + ac;

  for (int ks = 0; ks < IN_DIM / 32; ++ks) {
    // ---- stage A: 128x32 fp32 -> bf16 LDS [m][k], b64 writes (conflict-free)
    #pragma unroll
    for (int p = 0; p < 4; ++p) {
      const float4 v = *reinterpret_cast<const float4*>(aptr + (size_t)(p * 32) * IN_DIM);
      uint2 w;
      w.x = pack_bf16(v.x, v.y);
      w.y = pack_bf16(v.z, v.w);
      *reinterpret_cast<uint2*>(&As[(ar + p * 32) * 32 + ac]) = w;
    }

    // ---- stage B: 32x128 fp32 of W -> bf16 LDS [n][k], transposed.
    // 8 float2 loads (8 consecutive k-rows, one n-pair), 2 b128 writes.
    // Write banks uniform (8 accesses/bank per instr) -> no serialization.
    float2 v[8];
    #pragma unroll
    for (int r = 0; r < 8; ++r)
      v[r] = *reinterpret_cast<const float2*>(wptr + (size_t)r * HID_DIM);
    uint4 w0, w1;
    w0.x = pack_bf16(v[0].x, v[1].x); w0.y = pack_bf16(v[2].x, v[3].x);
    w0.z = pack_bf16(v[4].x, v[5].x); w0.w = pack_bf16(v[6].x, v[7].x);
    w1.x = pack_bf16(v[0].y, v[1].y); w1.y = pack_bf16(v[2].y, v[3].y);
    w1.z = pack_bf16(v[4].y, v[5].y); w1.w = pack_bf16(v[6].y, v[7].y);
    *reinterpret_cast<uint4*>(&Bs[(2 * u)     * 40 + g * 8]) = w0;
    *reinterpret_cast<uint4*>(&Bs[(2 * u + 1) * 40 + g * 8]) = w1;

    aptr += 32;
    wptr += (size_t)32 * HID_DIM;

    __syncthreads();

    // ---- fragments: A[m=l16][k=quad*8+j], B[k=quad*8+j][n=l16]
    shortx8 af[4], bfr[4];
    #pragma unroll
    for (int i = 0; i < 4; ++i)
      af[i] = *reinterpret_cast<const shortx8*>(&As[(wm + i * 16 + l16) * 32 + quad * 8]);
    #pragma unroll
    for (int j = 0; j < 4; ++j)
      bfr[j] = *reinterpret_cast<const shortx8*>(&Bs[(wn + j * 16 + l16) * 40 + quad * 8]);

    #pragma unroll
    for (int i = 0; i < 4; ++i) {
      #pragma unroll
      for (int j = 0; j < 4; ++j) {
        acc[i][j] = __builtin_amdgcn_mfma_f32_16x16x32_bf16(af[i], bfr[j], acc[i][j], 0, 0, 0);
      }
    }

    __syncthreads();
  }

  // ---- epilogue: C/D layout col=l16, row=quad*4+r; add bias, fp32 store
  float* outp = out + ((size_t)b * T_DIM + (size_t)mt * 128) * HID_DIM + n0;
  const float* bp = bias + (size_t)c * HID_DIM + n0;
  #pragma unroll
  for (int j = 0; j < 4; ++j) {
    const float bj = bp[wn + j * 16 + l16];
    #pragma unroll
    for (int i = 0; i < 4; ++i) {
      #pragma unroll
      for (int r = 0; r < 4; ++r) {
        const int m = wm + i * 16 + quad * 4 + r;
        outp[(size_t)m * HID_DIM + wn + j * 16 + l16] = acc[i][j][r] + bj;
      }
    }
  }
}

extern "C" void kernel_launch(void* const* d_in, const int* in_sizes, int n_in,
                              void* d_out, int out_size, void* d_ws, size_t ws_size,
                              hipStream_t stream) {
  const float* x    = (const float*)d_in[0];
  const int*   cat  = (const int*)d_in[1];
  const float* W    = (const float*)d_in[2];
  const float* bias = (const float*)d_in[3];
  float* out = (float*)d_out;

  dim3 grid(HID_DIM / 128, T_DIM / 128, 64);   // (16, 2, 64) = 2048 blocks
  hipLaunchKernelGGL(cat_linear_kernel, grid, dim3(256), 0, stream,
                     x, cat, W, bias, out);
}

// Round 3
// 530.496 us; speedup vs baseline: 1.1937x; 1.1937x over previous
//
#include <hip/hip_runtime.h>

#define IN_DIM 1024
#define HID_DIM 2048
#define T_DIM 256

typedef __attribute__((ext_vector_type(4))) float floatx4;
typedef __attribute__((ext_vector_type(8))) short shortx8;   // 8 bf16 (4 VGPRs)

__device__ __forceinline__ unsigned bf_rnd(float f) {
  // fp32 -> bf16 RNE, result in high 16 bits
  unsigned u = __builtin_bit_cast(unsigned, f);
  return u + 0x7fffu + ((u >> 16) & 1u);
}

// returns (bf16(fhi) << 16) | bf16(flo)  -- one v_perm_b32 for the pack
__device__ __forceinline__ unsigned pack_bf16(float flo, float fhi) {
  return __builtin_amdgcn_perm(bf_rnd(fhi), bf_rnd(flo), 0x07060302u);
}

__global__ __launch_bounds__(256) void cat_linear_kernel(
    const float* __restrict__ x, const int* __restrict__ cat_ids,
    const float* __restrict__ W, const float* __restrict__ bias,
    float* __restrict__ out) {
  const int nt = blockIdx.x;   // 0..15  (hidden tiles)
  const int mt = blockIdx.y;   // 0..1   (token tiles)
  const int b  = blockIdx.z;   // 0..63  (batch)
  const int tid = threadIdx.x;
  const int c = cat_ids[b];

  const int n0 = nt * 128;
  const float* xb = x + ((size_t)b * T_DIM + (size_t)mt * 128) * IN_DIM;
  const float* Wc = W + (size_t)c * IN_DIM * HID_DIM + n0;

  // A: [m][k] row-major, BK=32 (m97-proven, conflict-free both sides)
  __shared__ __attribute__((aligned(16))) unsigned short As[128 * 32];   // 8 KB
  // B: [n][k] transposed tile, 40-short rows (80B, 16B-aligned), with XOR
  // chunk swizzle: 16B chunk c of row n stored at position c ^ ((n>>3)&3).
  // Write banks: 16(t&1)+4((t>>1)&3)+kp -> 32 banks x 2 lanes = free (m136).
  __shared__ __attribute__((aligned(16))) unsigned short Bs[128 * 40];   // 10 KB

  const int lane = tid & 63;
  const int wv   = tid >> 6;         // wave 0..3 -> 2x2
  const int wm   = (wv >> 1) * 64;
  const int wn   = (wv & 1) * 64;
  const int l16  = lane & 15;
  const int quad = lane >> 4;

  floatx4 acc[4][4] = {};

  // A staging: thread covers row ar(+p*32), 4 k-cols (float4, coalesced)
  const int ar = tid >> 3;
  const int ac = (tid & 7) * 4;
  // B staging: thread covers k-pair kp (rows 2kp,2kp+1), 4 consecutive n
  const int kp = tid >> 4;           // 0..15
  const int bn = (tid & 15) * 4;     // 0..60 (+q*64)
  const int bswz = ((tid & 15) >> 1) & 3;      // s(n) for this thread's n's (const over e,q)
  const int bcol = 8 * ((kp >> 2) ^ bswz) + 2 * (kp & 3);   // swizzled short offset in row

  const float* aptr = xb + (size_t)ar * IN_DIM + ac;

  for (int ks = 0; ks < IN_DIM / 32; ++ks) {
    const int k0 = ks * 32;

    // ---- stage A: 128x32 fp32 -> bf16 LDS [m][k], b64 writes (uniform banks)
    #pragma unroll
    for (int p = 0; p < 4; ++p) {
      const float4 v = *reinterpret_cast<const float4*>(aptr + (size_t)(p * 32) * IN_DIM);
      uint2 w;
      w.x = pack_bf16(v.x, v.y);
      w.y = pack_bf16(v.z, v.w);
      *reinterpret_cast<uint2*>(&As[(ar + p * 32) * 32 + ac]) = w;
    }

    // ---- stage B: 32x128 fp32 of W -> bf16 LDS [n][k] transposed, swizzled.
    // Coalesced float4 loads (16B/lane): rows 2kp,2kp+1, cols bn..bn+3.
    #pragma unroll
    for (int q = 0; q < 2; ++q) {
      const int n = bn + q * 64;
      const float4 v0 = *reinterpret_cast<const float4*>(Wc + (size_t)(k0 + 2 * kp)     * HID_DIM + n);
      const float4 v1 = *reinterpret_cast<const float4*>(Wc + (size_t)(k0 + 2 * kp + 1) * HID_DIM + n);
      *reinterpret_cast<unsigned*>(&Bs[(n + 0) * 40 + bcol]) = pack_bf16(v0.x, v1.x);
      *reinterpret_cast<unsigned*>(&Bs[(n + 1) * 40 + bcol]) = pack_bf16(v0.y, v1.y);
      *reinterpret_cast<unsigned*>(&Bs[(n + 2) * 40 + bcol]) = pack_bf16(v0.z, v1.z);
      *reinterpret_cast<unsigned*>(&Bs[(n + 3) * 40 + bcol]) = pack_bf16(v0.w, v1.w);
    }

    aptr += 32;

    __syncthreads();

    // ---- fragments: A[m=l16][k=quad*8+j], B[k=quad*8+j][n=l16]
    shortx8 af[4], bfr[4];
    #pragma unroll
    for (int i = 0; i < 4; ++i)
      af[i] = *reinterpret_cast<const shortx8*>(&As[(wm + i * 16 + l16) * 32 + quad * 8]);
    #pragma unroll
    for (int j = 0; j < 4; ++j) {
      const int n = wn + j * 16 + l16;
      const int s = (n >> 3) & 3;
      bfr[j] = *reinterpret_cast<const shortx8*>(&Bs[n * 40 + 8 * (quad ^ s)]);
    }

    #pragma unroll
    for (int i = 0; i < 4; ++i) {
      #pragma unroll
      for (int j = 0; j < 4; ++j) {
        acc[i][j] = __builtin_amdgcn_mfma_f32_16x16x32_bf16(af[i], bfr[j], acc[i][j], 0, 0, 0);
      }
    }

    __syncthreads();
  }

  // ---- epilogue: C/D layout col=l16, row=quad*4+r; add bias, fp32 store
  float* outp = out + ((size_t)b * T_DIM + (size_t)mt * 128) * HID_DIM + n0;
  const float* bp = bias + (size_t)c * HID_DIM + n0;
  #pragma unroll
  for (int j = 0; j < 4; ++j) {
    const float bj = bp[wn + j * 16 + l16];
    #pragma unroll
    for (int i = 0; i < 4; ++i) {
      #pragma unroll
      for (int r = 0; r < 4; ++r) {
        const int m = wm + i * 16 + quad * 4 + r;
        outp[(size_t)m * HID_DIM + wn + j * 16 + l16] = acc[i][j][r] + bj;
      }
    }
  }
}

extern "C" void kernel_launch(void* const* d_in, const int* in_sizes, int n_in,
                              void* d_out, int out_size, void* d_ws, size_t ws_size,
                              hipStream_t stream) {
  const float* x    = (const float*)d_in[0];
  const int*   cat  = (const int*)d_in[1];
  const float* W    = (const float*)d_in[2];
  const float* bias = (const float*)d_in[3];
  float* out = (float*)d_out;

  dim3 grid(HID_DIM / 128, T_DIM / 128, 64);   // (16, 2, 64) = 2048 blocks
  hipLaunchKernelGGL(cat_linear_kernel, grid, dim3(256), 0, stream,
                     x, cat, W, bias, out);
}